// Round 10
// baseline (3660.285 us; speedup 1.0000x reference)
//
#include <hip/hip_runtime.h>
#include <hip/hip_bf16.h>

#define T_SEQ 256
#define BATCH 256
#define HID   1024
#define EMB   10
#define VOCABN 10
#define NCLS  10

typedef __attribute__((ext_vector_type(8))) short short8;
typedef __attribute__((ext_vector_type(4))) float floatx4;
typedef unsigned long long ull;

// ---- workspace layout (bytes) ----
#define OFF_WHB   0                                // 4096*1024 bf16 = 8 MB
#define OFF_PTAB  (8*1024*1024)                    // 10*4096 f32 = 160 KB
#define OFF_H0    (OFF_PTAB + 160*1024)            // 256*1024 bf16 = 512 KB
#define OFF_H1    (OFF_H0 + BATCH*HID*2)
#define OFF_BAR   (OFF_H1 + BATCH*HID*2)           // [0,1024) per-wave flags; [1024,1280) XCD slot ctrs (1/line)

// Spin bound: converts any broken-link hang into a diagnosable
// failed-verification run instead of a harness timeout (r3 lesson).
#define SPIN_BOUND (1u << 17)

// hwreg(HW_REG_XCC_ID=20, offset=0, width=32) -> 20 | (31<<11) = 63508
#define HWREG_XCC_ID_FULL 63508

__device__ __forceinline__ float fsig(float x) {
    return __builtin_amdgcn_rcpf(1.0f + __expf(-x));
}
__device__ __forceinline__ float ftanh(float x) {
    return 2.0f * fsig(2.0f * x) - 1.0f;
}

// TCC-executed atomic add returning old value (L1-immune true L2 read).
// PMC accounting (r6/r8/r9): every TCC RMW = one fabric transaction, and
// SAME-ADDRESS RMWs serialize (~100cy each). Distinct-address RMWs don't.
__device__ __forceinline__ unsigned atomic_add_ret_l2(unsigned* p, unsigned v) {
    unsigned old;
    asm volatile("global_atomic_add %0, %1, %2, off sc0\n\ts_waitcnt vmcnt(0)"
                 : "=v"(old) : "v"(p), "v"(v) : "memory");
    return old;
}
__device__ __forceinline__ void atomic_add_l2(unsigned* p, unsigned v) {
    asm volatile("global_atomic_add %0, %1, off" :: "v"(p), "v"(v) : "memory");
}

// One-shot prep: cast Wh -> bf16 gate-major; build ptab; zero h0/h1 + flags.
__global__ __launch_bounds__(256)
void prep_kernel(const float* __restrict__ Wgh, const float* __restrict__ Wih,
                 const float* __restrict__ Wfh, const float* __restrict__ Woh,
                 const float* __restrict__ embed,
                 const float* __restrict__ Wgx, const float* __restrict__ Wix,
                 const float* __restrict__ Wfx, const float* __restrict__ Wox,
                 const float* __restrict__ bg, const float* __restrict__ bi,
                 const float* __restrict__ bf, const float* __restrict__ bo,
                 __hip_bfloat16* __restrict__ whb, float* __restrict__ ptab,
                 __hip_bfloat16* __restrict__ h0, __hip_bfloat16* __restrict__ h1,
                 unsigned* __restrict__ bar)
{
    int idx = blockIdx.x * 256 + threadIdx.x;   // 0 .. 4194303
    {
        int gate = idx >> 20;
        int rem  = idx & 0xFFFFF;
        const float* W = (gate == 0) ? Wgh : (gate == 1) ? Wih : (gate == 2) ? Wfh : Woh;
        whb[idx] = __float2bfloat16(W[rem]);
    }
    if (idx < VOCABN * 4 * HID) {               // ptab[v*4096 + g]
        int v = idx >> 12;
        int g = idx & 4095;
        int gg = g >> 10;
        int j  = g & 1023;
        const float* Wx = (gg == 0) ? Wgx : (gg == 1) ? Wix : (gg == 2) ? Wfx : Wox;
        const float* bb = (gg == 0) ? bg  : (gg == 1) ? bi  : (gg == 2) ? bf  : bo;
        float s = bb[j];
        #pragma unroll
        for (int e = 0; e < EMB; ++e) s += embed[v * EMB + e] * Wx[j * EMB + e];
        ptab[idx] = s;
    }
    if (idx < BATCH * HID) {
        h0[idx] = __float2bfloat16(0.0f);
        h1[idx] = __float2bfloat16(0.0f);       // insurance: bounded values if raced
    }
    if (idx < 1280) bar[idx] = 0u;              // flags + padded slot ctrs
}

// Persistent LSTM, weights stationary in registers for all 256 timesteps.
// Grid 256 WGs x 256 thr; ~117KB LDS -> 1 WG/CU forced; 256 CUs -> pigeonhole
// gives exactly 32 WGs per XCD. Each WG reads its physical XCD (s_getreg
// XCC_ID) and claims (bt=xcd, ht=slot): producers/consumers of a batch group
// share one XCD; the h exchange lives entirely in that XCD's L2.
//   - h stores: plain (write-through L1 -> local L2; vmcnt(0) ack => visible).
//   - sync: DISTRIBUTED FLAGS. Producer wave (bt,ht,w) owns flag word
//     FLAG[bt][ht>>3][ht&7][w]; after its h-drain it atomic-adds 1 to ITS OWN
//     word (distinct addresses -> no TCC serialization; r6 hammered one
//     counter with 32 signal-RMWs + ~40 poll-RMWs, all serialized ~100cy =
//     ~7k cy/step). Consumer wave w polls its quarter's 32 words with one
//     coalesced 64-lane `sc0` load (single 128B L2 transaction, no RMW, no
//     fabric traffic) + __all vote; every 4th iteration = lane-parallel
//     atomic RMW fallback (liveness even if sc0 loads were L1-cached; then
//     detect lag <= 4 iters ~= r6 behavior, bounded regression).
//     NOTE r3's "sc0 load doesn't bypass L1" evidence is INVALID (r3 had the
//     cross-XCD slot-claim false-sharing bug, fixed r4); r7's flag failure
//     is confounded by its missing post-inv s_waitcnt (r6/r8/r9 all pass
//     with it). Monotone flags: a stale under-read only delays, never lies.
//   - A-loads: ONE buffer_inv sc0 + s_waitcnt vmcnt(0) per wave per step,
//     then 16 plain dwordx4 in one L2 round trip (r6-proven).
//   - x staged in LDS once (r9-proven): immune to the per-step L1 inv.
// WAR on the h ping-pong is transitive: step-t+2 stores of buffer P happen
// after observing all 32 step-t+1 flags; each flag postdates that WG's t+1
// reduction barrier, which postdates its step-t A-loads of P retiring.
__global__ __launch_bounds__(256, 1)
void lstm_persist(const int* __restrict__ x, const float* __restrict__ ptab,
                  const __hip_bfloat16* __restrict__ whb,
                  __hip_bfloat16* __restrict__ h0buf,
                  __hip_bfloat16* __restrict__ h1buf,
                  unsigned* __restrict__ bar)
{
    __shared__ float red[4 * 2 * 8 * 320];   // [wave][m][n][col*20+row] = 80 KB
    __shared__ float pt[VOCABN * 128];       // [v][g][jj2] = 5 KB
    __shared__ int   xs[32 * T_SEQ];         // [row][t] = 32 KB
    __shared__ int s_grp[2];

    const int tid  = threadIdx.x;
    const int w    = tid >> 6;
    const int lane = tid & 63;
    const int l16  = lane & 15;
    const int quad = lane >> 4;

    // ---- runtime XCD discovery + slot claim (correct under ANY dispatch map).
    if (tid == 0) {
        unsigned xcd = __builtin_amdgcn_s_getreg(HWREG_XCC_ID_FULL) & 7u;
        unsigned slot = atomic_add_ret_l2(bar + 1024 + xcd * 32, 1u);
        s_grp[0] = (int)xcd;
        s_grp[1] = (int)(slot & 31u);
    }
    __syncthreads();
    const int bt = s_grp[0];                  // batch group == physical XCD
    const int ht = s_grp[1];                  // 0..31 hidden tile (claim order)
    const int j0 = ht << 5;
    const int b0 = bt << 5;
    const int mw = w >> 1;                    // owned m-tile (post-reduction)
    const int jb = w & 1;                     // owned 16-col half of the 32-hid tile

    // Flags: 32 words per (bt, quarter); one word per producer wave.
    unsigned* myflags = bar + ((bt << 2) + w) * 32;                      // polled (quarter w)
    unsigned* sigflag = bar + ((bt << 2) + (ht >> 3)) * 32 + ((ht & 7) << 2) + w;  // owned

    // Stage ptab slice: pt[v*128 + g*32 + jj2]
    for (int i = tid; i < VOCABN * 128; i += 256) {
        int v = i >> 7, r = i & 127, g = r >> 5, jj2 = r & 31;
        pt[i] = ptab[v * 4096 + g * 1024 + j0 + jj2];
    }
    // Stage this group's x rows: xs[row*256 + t], coalesced.
    for (int i = tid; i < 32 * T_SEQ; i += 256) {
        int row = i >> 8, tt = i & 255;
        xs[i] = x[(b0 + row) * T_SEQ + tt];
    }

    // Stationary B fragments: n-frag n -> gate n>>1, col-half (n&1)*16.
    short8 Bf[8][8];
    #pragma unroll
    for (int n = 0; n < 8; ++n) {
        const short* p = (const short*)whb + (((size_t)(n >> 1)) << 20)
                       + (((size_t)(j0 + ((n & 1) << 4) + l16)) << 10)
                       + (w << 8) + (quad << 3);
        #pragma unroll
        for (int kc = 0; kc < 8; ++kc)
            Bf[n][kc] = *(const short8*)(p + kc * 32);
    }

    float cst[4] = {0.f, 0.f, 0.f, 0.f};
    __syncthreads();                          // pt + xs ready

    ull hinA  = (ull)h0buf;
    ull houtA = (ull)h1buf;
    const int brow = (mw << 4) + (quad << 2); // owned batch-row base (local)

    #pragma unroll 1
    for (int t = 0; t < T_SEQ; ++t) {
        // x fetch from LDS (independent of h readiness, inv-immune).
        int xv[4];
        #pragma unroll
        for (int r = 0; r < 4; ++r) xv[r] = xs[(brow + r) * T_SEQ + t];

        // ---- per-wave spin: all 32 producer-wave flags of quarter w >= t.
        // Coalesced 64-lane sc0 load (lanes>=32 mirror 0..31) = one L2
        // transaction; every 4th iteration = distinct-address atomic RMW
        // fallback (guaranteed-fresh; bounds staleness to <=4 iterations).
        if (t) {
            unsigned* fl = myflags + (lane & 31);
            unsigned tgt = (unsigned)t;
            for (unsigned it = 0; it < SPIN_BOUND; ++it) {
                unsigned v;
                if ((it & 3) == 3) {
                    v = atomic_add_ret_l2(fl, 0u);
                } else {
                    asm volatile("global_load_dword %0, %1, off sc0\n\t"
                                 "s_waitcnt vmcnt(0)"
                                 : "=v"(v) : "v"(fl) : "memory");
                }
                if (__all((int)(v >= tgt))) break;
                __builtin_amdgcn_s_sleep(1);
            }
            // ONE L1-only invalidate per wave per step (completion waited) so
            // the plain A-loads below refill from the fresh local L2
            // (r6-proven; r7's corruption = this waitcnt missing).
            asm volatile("buffer_inv sc0\n\ts_waitcnt vmcnt(0)" ::: "memory");
        }

        // ---- A-fragment loads: all 16 plain loads in flight, ONE L2 round trip.
        const ull* Au = (const ull*)hinA + (((size_t)(b0 + l16)) << 8) + (w << 6) + (quad << 1);
        short8 Af[2][8];
        #pragma unroll
        for (int kc = 0; kc < 8; ++kc)
            Af[0][kc] = *(const short8*)(Au + kc * 8);
        #pragma unroll
        for (int kc = 0; kc < 8; ++kc)
            Af[1][kc] = *(const short8*)(Au + 4096 + kc * 8);

        // ---- partial GEMM over this wave's K-slice: 2 m-tiles x 8 n-frags.
        floatx4 acc[2][8];
        #pragma unroll
        for (int m = 0; m < 2; ++m) {
            #pragma unroll
            for (int n = 0; n < 8; ++n) {
                floatx4 a = {0.f, 0.f, 0.f, 0.f};
                #pragma unroll
                for (int kc = 0; kc < 8; ++kc)
                    a = __builtin_amdgcn_mfma_f32_16x16x32_bf16(Af[m][kc], Bf[n][kc], a, 0, 0, 0);
                acc[m][n] = a;
            }
        }

        // ---- K-reduction through LDS; wave w owns (m=mw, col-half jb).
        #pragma unroll
        for (int m = 0; m < 2; ++m)
            #pragma unroll
            for (int n = 0; n < 8; ++n)
                *(floatx4*)&red[(((w * 2 + m) * 8 + n) * 320) + l16 * 20 + quad * 4] = acc[m][n];
        __syncthreads();

        floatx4 z[4];
        #pragma unroll
        for (int g = 0; g < 4; ++g) {
            int n = (g << 1) + jb;
            floatx4 s = *(floatx4*)&red[((mw * 8 + n) * 320) + l16 * 20 + quad * 4];
            #pragma unroll
            for (int wp = 1; wp < 4; ++wp)
                s += *(floatx4*)&red[(((wp * 2 + mw) * 8 + n) * 320) + l16 * 20 + quad * 4];
            z[g] = s;
        }

        // ---- gates + register-resident c + plain h store (write-through to local L2).
        __hip_bfloat16* ho = (__hip_bfloat16*)houtA;
        const int jcol = j0 + (jb << 4) + l16;
        #pragma unroll
        for (int r = 0; r < 4; ++r) {
            int pb = (xv[r] << 7) + (jb << 4) + l16;
            float zg = z[0][r] + pt[pb];
            float zi = z[1][r] + pt[pb + 32];
            float zf = z[2][r] + pt[pb + 64];
            float zo = z[3][r] + pt[pb + 96];
            float gv = ftanh(zg), iv = fsig(zi), fv = fsig(zf), ov = fsig(zo);
            float cn = gv * iv + cst[r] * fv;
            cst[r] = cn;
            ho[(((size_t)(b0 + brow + r)) << 10) + jcol] = __float2bfloat16(ftanh(cn) * ov);
        }

        // ---- per-wave early signal: drain THIS wave's h stores to the local
        // L2 (store-ack from TCC), then bump OWN flag word (no contention).
        if (t != T_SEQ - 1) {
            asm volatile("s_waitcnt vmcnt(0)" ::: "memory");
            if (lane == 0)
                atomic_add_l2(sigflag, 1u);
        }

        // red-buffer WAR protection for the next step (off the signal path).
        __syncthreads();

        ull tmp = hinA; hinA = houtA; houtA = tmp;
    }
}

// y = h @ W_ph^T + b_p : one wave per batch row.
__global__ __launch_bounds__(256)
void final_kernel(const __hip_bfloat16* __restrict__ h, const float* __restrict__ Wph,
                  const float* __restrict__ bp, float* __restrict__ y)
{
    int w = threadIdx.x >> 6;
    int lane = threadIdx.x & 63;
    int b = blockIdx.x * 4 + w;
    float acc[NCLS];
    #pragma unroll
    for (int k = 0; k < NCLS; ++k) acc[k] = 0.0f;
    for (int k = lane; k < HID; k += 64) {
        float hv = __bfloat162float(h[b * HID + k]);
        #pragma unroll
        for (int cls = 0; cls < NCLS; ++cls) acc[cls] += hv * Wph[cls * HID + k];
    }
    #pragma unroll
    for (int cls = 0; cls < NCLS; ++cls) {
        float v = acc[cls];
        #pragma unroll
        for (int off = 32; off > 0; off >>= 1) v += __shfl_down(v, off);
        if (lane == 0) y[b * NCLS + cls] = v + bp[cls];
    }
}

extern "C" void kernel_launch(void* const* d_in, const int* in_sizes, int n_in,
                              void* d_out, int out_size, void* d_ws, size_t ws_size,
                              hipStream_t stream)
{
    const int*   x     = (const int*)d_in[0];
    const float* embed = (const float*)d_in[1];
    const float* Wgx   = (const float*)d_in[2];
    const float* Wix   = (const float*)d_in[3];
    const float* Wfx   = (const float*)d_in[4];
    const float* Wox   = (const float*)d_in[5];
    const float* Wgh   = (const float*)d_in[6];
    const float* Wih   = (const float*)d_in[7];
    const float* Wfh   = (const float*)d_in[8];
    const float* Woh   = (const float*)d_in[9];
    const float* Wph   = (const float*)d_in[10];
    const float* bg    = (const float*)d_in[11];
    const float* bi    = (const float*)d_in[12];
    const float* bf    = (const float*)d_in[13];
    const float* bo    = (const float*)d_in[14];
    const float* bp    = (const float*)d_in[15];
    float* out = (float*)d_out;

    char* ws = (char*)d_ws;
    __hip_bfloat16* whb  = (__hip_bfloat16*)(ws + OFF_WHB);
    float*          ptab = (float*)(ws + OFF_PTAB);
    __hip_bfloat16* h0   = (__hip_bfloat16*)(ws + OFF_H0);
    __hip_bfloat16* h1   = (__hip_bfloat16*)(ws + OFF_H1);
    unsigned*       bar  = (unsigned*)(ws + OFF_BAR);

    prep_kernel<<<16384, 256, 0, stream>>>(Wgh, Wih, Wfh, Woh, embed,
                                           Wgx, Wix, Wfx, Wox,
                                           bg, bi, bf, bo,
                                           whb, ptab, h0, h1, bar);

    lstm_persist<<<256, 256, 0, stream>>>(x, ptab, whb, h0, h1, bar);

    // T=256 even -> final h lives in h0.
    final_kernel<<<64, 256, 0, stream>>>(h0, Wph, bp, out);
}

// Round 11
// 2130.910 us; speedup vs baseline: 1.7177x; 1.7177x over previous
//
#include <hip/hip_runtime.h>
#include <hip/hip_bf16.h>

#define T_SEQ 256
#define BATCH 256
#define HID   1024
#define EMB   10
#define VOCABN 10
#define NCLS  10

typedef __attribute__((ext_vector_type(8))) short short8;
typedef __attribute__((ext_vector_type(4))) float floatx4;
typedef unsigned long long ull;

// ---- workspace layout (bytes) ----
#define OFF_WHB   0                                // 4096*1024 bf16 = 8 MB
#define OFF_PTAB  (8*1024*1024)                    // 10*4096 f32 = 160 KB
#define OFF_H0    (OFF_PTAB + 160*1024)            // 256*1024 bf16 = 512 KB
#define OFF_H1    (OFF_H0 + BATCH*HID*2)
#define OFF_BAR   (OFF_H1 + BATCH*HID*2)           // [0,1024) quarter ctrs; [1024,1280) XCD slot ctrs (1/line)

// Spin bound: converts any broken-link hang into a diagnosable
// failed-verification run instead of a harness timeout (r3 lesson).
#define SPIN_BOUND (1u << 17)

// hwreg(HW_REG_XCC_ID=20, offset=0, width=32) -> 20 | (31<<11) = 63508
#define HWREG_XCC_ID_FULL 63508

__device__ __forceinline__ float fsig(float x) {
    return __builtin_amdgcn_rcpf(1.0f + __expf(-x));
}
__device__ __forceinline__ float ftanh(float x) {
    return 2.0f * fsig(2.0f * x) - 1.0f;
}

// TCC-executed atomic add returning old value (L1-immune true L2 read).
// PMC accounting (r6/r8/r9/r10): every TCC RMW = one fabric transaction and
// same-address RMWs serialize (~100cy). Use ONLY: slot claim, per-WG signals
// (8/ctr/step), and the poll fallback phase.
__device__ __forceinline__ unsigned atomic_add_ret_l2(unsigned* p, unsigned v) {
    unsigned old;
    asm volatile("global_atomic_add %0, %1, %2, off sc0\n\ts_waitcnt vmcnt(0)"
                 : "=v"(old) : "v"(p), "v"(v) : "memory");
    return old;
}
__device__ __forceinline__ void atomic_add_l2(unsigned* p, unsigned v) {
    asm volatile("global_atomic_add %0, %1, off" :: "v"(p), "v"(v) : "memory");
}

// One-shot prep: cast Wh -> bf16 gate-major; build ptab; zero h0/h1 + counters.
__global__ __launch_bounds__(256)
void prep_kernel(const float* __restrict__ Wgh, const float* __restrict__ Wih,
                 const float* __restrict__ Wfh, const float* __restrict__ Woh,
                 const float* __restrict__ embed,
                 const float* __restrict__ Wgx, const float* __restrict__ Wix,
                 const float* __restrict__ Wfx, const float* __restrict__ Wox,
                 const float* __restrict__ bg, const float* __restrict__ bi,
                 const float* __restrict__ bf, const float* __restrict__ bo,
                 __hip_bfloat16* __restrict__ whb, float* __restrict__ ptab,
                 __hip_bfloat16* __restrict__ h0, __hip_bfloat16* __restrict__ h1,
                 unsigned* __restrict__ bar)
{
    int idx = blockIdx.x * 256 + threadIdx.x;   // 0 .. 4194303
    {
        int gate = idx >> 20;
        int rem  = idx & 0xFFFFF;
        const float* W = (gate == 0) ? Wgh : (gate == 1) ? Wih : (gate == 2) ? Wfh : Woh;
        whb[idx] = __float2bfloat16(W[rem]);
    }
    if (idx < VOCABN * 4 * HID) {               // ptab[v*4096 + g]
        int v = idx >> 12;
        int g = idx & 4095;
        int gg = g >> 10;
        int j  = g & 1023;
        const float* Wx = (gg == 0) ? Wgx : (gg == 1) ? Wix : (gg == 2) ? Wfx : Wox;
        const float* bb = (gg == 0) ? bg  : (gg == 1) ? bi  : (gg == 2) ? bf  : bo;
        float s = bb[j];
        #pragma unroll
        for (int e = 0; e < EMB; ++e) s += embed[v * EMB + e] * Wx[j * EMB + e];
        ptab[idx] = s;
    }
    if (idx < BATCH * HID) {
        h0[idx] = __float2bfloat16(0.0f);
        h1[idx] = __float2bfloat16(0.0f);       // insurance: bounded values if raced
    }
    if (idx < 1280) bar[idx] = 0u;              // quarter ctrs + padded slot ctrs
}

// Persistent LSTM, weights stationary in registers for all 256 timesteps.
// Grid 256 WGs x 256 thr; ~117KB LDS -> 1 WG/CU forced; 256 CUs -> pigeonhole
// gives exactly 32 WGs per XCD. Each WG reads its physical XCD (s_getreg
// XCC_ID) and claims (bt=xcd, ht=slot): producers/consumers of a batch group
// share one XCD; the h exchange lives entirely in that XCD's L2.
//   - h stores: plain (write-through L1 -> local L2). __syncthreads drains
//     each wave's vmcnt(0) -> all 4 waves' h-stores L2-visible at the barrier.
//   - signal: ONE atomic per WG per step (tid0, post-barrier; r9-proven
//     correct, cuts signal RMWs 32->8 per counter per step, WRITE 21.9->3MB).
//   - poll: lane0, TWO-PHASE. Iter 0..5: `sc0` load (single cheap L2 read;
//     no RMW -> no fabric write, no TCC serialization). Iter >=6: r6-proven
//     atomic RMW (guaranteed fresh). Monotone counter: a stale load only
//     under-reads (delays), never fabricates >= tgt -> safe either way.
//     If sc0 loads are fresh (r3/r7 contrary evidence is confounded: r3 had
//     the cross-XCD false-sharing claim bug, r7 a missing post-inv waitcnt),
//     steady-state polling is RMW-free; if stale, we fall into exactly r6's
//     proven poll after ~400cy. NO per-iteration buffer_inv (r8: poison) and
//     NO nt (r9: reads stale memory-side copy, misses dirty L2 lines).
//   - A-loads: ONE buffer_inv sc0 + s_waitcnt vmcnt(0) per wave per step,
//     then 16 plain dwordx4 in one L2 round trip (r6-proven).
//   - x staged in LDS once (r9-proven): immune to the per-step L1 inv.
// WAR on the h ping-pong is transitive: step-t+2 stores of buffer P happen
// after this WG's 4 spins observed all 8 per-WG step-t+1 signals of every
// quarter (union = all 32 WGs); each signal postdates that WG's t+1 final
// barrier, which postdates its step-t+1... (and hence t) A-loads retiring.
__global__ __launch_bounds__(256, 1)
void lstm_persist(const int* __restrict__ x, const float* __restrict__ ptab,
                  const __hip_bfloat16* __restrict__ whb,
                  __hip_bfloat16* __restrict__ h0buf,
                  __hip_bfloat16* __restrict__ h1buf,
                  unsigned* __restrict__ bar)
{
    __shared__ float red[4 * 2 * 8 * 320];   // [wave][m][n][col*20+row] = 80 KB
    __shared__ float pt[VOCABN * 128];       // [v][g][jj2] = 5 KB
    __shared__ int   xs[32 * T_SEQ];         // [row][t] = 32 KB
    __shared__ int s_grp[2];

    const int tid  = threadIdx.x;
    const int w    = tid >> 6;
    const int lane = tid & 63;
    const int l16  = lane & 15;
    const int quad = lane >> 4;

    // ---- runtime XCD discovery + slot claim (correct under ANY dispatch map).
    if (tid == 0) {
        unsigned xcd = __builtin_amdgcn_s_getreg(HWREG_XCC_ID_FULL) & 7u;
        unsigned slot = atomic_add_ret_l2(bar + 1024 + xcd * 32, 1u);
        s_grp[0] = (int)xcd;
        s_grp[1] = (int)(slot & 31u);
    }
    __syncthreads();
    const int bt = s_grp[0];                  // batch group == physical XCD
    const int ht = s_grp[1];                  // 0..31 hidden tile (claim order)
    const int j0 = ht << 5;
    const int b0 = bt << 5;
    const int mw = w >> 1;                    // owned m-tile (post-reduction)
    const int jb = w & 1;                     // owned 16-col half of the 32-hid tile

    unsigned* myq  = bar + ((bt << 2) + w) * 32;          // quarter this wave consumes
    unsigned* sigq = bar + ((bt << 2) + (ht >> 3)) * 32;  // quarter this WG produces

    // Stage ptab slice: pt[v*128 + g*32 + jj2]
    for (int i = tid; i < VOCABN * 128; i += 256) {
        int v = i >> 7, r = i & 127, g = r >> 5, jj2 = r & 31;
        pt[i] = ptab[v * 4096 + g * 1024 + j0 + jj2];
    }
    // Stage this group's x rows: xs[row*256 + t], coalesced.
    for (int i = tid; i < 32 * T_SEQ; i += 256) {
        int row = i >> 8, tt = i & 255;
        xs[i] = x[(b0 + row) * T_SEQ + tt];
    }

    // Stationary B fragments: n-frag n -> gate n>>1, col-half (n&1)*16.
    short8 Bf[8][8];
    #pragma unroll
    for (int n = 0; n < 8; ++n) {
        const short* p = (const short*)whb + (((size_t)(n >> 1)) << 20)
                       + (((size_t)(j0 + ((n & 1) << 4) + l16)) << 10)
                       + (w << 8) + (quad << 3);
        #pragma unroll
        for (int kc = 0; kc < 8; ++kc)
            Bf[n][kc] = *(const short8*)(p + kc * 32);
    }

    float cst[4] = {0.f, 0.f, 0.f, 0.f};
    __syncthreads();                          // pt + xs ready

    ull hinA  = (ull)h0buf;
    ull houtA = (ull)h1buf;
    const int brow = (mw << 4) + (quad << 2); // owned batch-row base (local)

    #pragma unroll 1
    for (int t = 0; t < T_SEQ; ++t) {
        // x fetch from LDS (independent of h readiness, inv-immune).
        int xv[4];
        #pragma unroll
        for (int r = 0; r < 4; ++r) xv[r] = xs[(brow + r) * T_SEQ + t];

        // ---- per-wave two-phase spin on the quarter-w counter (target 8t).
        if (t) {
            unsigned tgt = (unsigned)(t << 3);
            if (lane == 0) {
                for (unsigned it = 0; it < SPIN_BOUND; ++it) {
                    unsigned vv;
                    if (it < 6) {
                        asm volatile("global_load_dword %0, %1, off sc0\n\t"
                                     "s_waitcnt vmcnt(0)"
                                     : "=v"(vv) : "v"(myq) : "memory");
                    } else {
                        vv = atomic_add_ret_l2(myq, 0u);
                    }
                    if (vv >= tgt) break;
                    __builtin_amdgcn_s_sleep(1);
                }
            }
            // ONE L1-only invalidate per wave per step (completion waited) so
            // the plain A-loads below refill from the fresh local L2
            // (r6-proven; r7's corruption = this waitcnt missing).
            asm volatile("buffer_inv sc0\n\ts_waitcnt vmcnt(0)" ::: "memory");
        }

        // ---- A-fragment loads: all 16 plain loads in flight, ONE L2 round trip.
        const ull* Au = (const ull*)hinA + (((size_t)(b0 + l16)) << 8) + (w << 6) + (quad << 1);
        short8 Af[2][8];
        #pragma unroll
        for (int kc = 0; kc < 8; ++kc)
            Af[0][kc] = *(const short8*)(Au + kc * 8);
        #pragma unroll
        for (int kc = 0; kc < 8; ++kc)
            Af[1][kc] = *(const short8*)(Au + 4096 + kc * 8);

        // ---- partial GEMM over this wave's K-slice: 2 m-tiles x 8 n-frags.
        floatx4 acc[2][8];
        #pragma unroll
        for (int m = 0; m < 2; ++m) {
            #pragma unroll
            for (int n = 0; n < 8; ++n) {
                floatx4 a = {0.f, 0.f, 0.f, 0.f};
                #pragma unroll
                for (int kc = 0; kc < 8; ++kc)
                    a = __builtin_amdgcn_mfma_f32_16x16x32_bf16(Af[m][kc], Bf[n][kc], a, 0, 0, 0);
                acc[m][n] = a;
            }
        }

        // ---- K-reduction through LDS; wave w owns (m=mw, col-half jb).
        #pragma unroll
        for (int m = 0; m < 2; ++m)
            #pragma unroll
            for (int n = 0; n < 8; ++n)
                *(floatx4*)&red[(((w * 2 + m) * 8 + n) * 320) + l16 * 20 + quad * 4] = acc[m][n];
        __syncthreads();

        floatx4 z[4];
        #pragma unroll
        for (int g = 0; g < 4; ++g) {
            int n = (g << 1) + jb;
            floatx4 s = *(floatx4*)&red[((mw * 8 + n) * 320) + l16 * 20 + quad * 4];
            #pragma unroll
            for (int wp = 1; wp < 4; ++wp)
                s += *(floatx4*)&red[(((wp * 2 + mw) * 8 + n) * 320) + l16 * 20 + quad * 4];
            z[g] = s;
        }

        // ---- gates + register-resident c + plain h store (write-through to local L2).
        __hip_bfloat16* ho = (__hip_bfloat16*)houtA;
        const int jcol = j0 + (jb << 4) + l16;
        #pragma unroll
        for (int r = 0; r < 4; ++r) {
            int pb = (xv[r] << 7) + (jb << 4) + l16;
            float zg = z[0][r] + pt[pb];
            float zi = z[1][r] + pt[pb + 32];
            float zf = z[2][r] + pt[pb + 64];
            float zo = z[3][r] + pt[pb + 96];
            float gv = ftanh(zg), iv = fsig(zi), fv = fsig(zf), ov = fsig(zo);
            float cn = gv * iv + cst[r] * fv;
            cst[r] = cn;
            ho[(((size_t)(b0 + brow + r)) << 10) + jcol] = __float2bfloat16(ftanh(cn) * ov);
        }

        // ---- barrier drains every wave's h-stores (vmcnt(0) before s_barrier)
        // and protects the red buffer; THEN one per-WG signal (r9-proven).
        __syncthreads();
        if (t != T_SEQ - 1 && tid == 0)
            atomic_add_l2(sigq, 1u);

        ull tmp = hinA; hinA = houtA; houtA = tmp;
    }
}

// y = h @ W_ph^T + b_p : one wave per batch row.
__global__ __launch_bounds__(256)
void final_kernel(const __hip_bfloat16* __restrict__ h, const float* __restrict__ Wph,
                  const float* __restrict__ bp, float* __restrict__ y)
{
    int w = threadIdx.x >> 6;
    int lane = threadIdx.x & 63;
    int b = blockIdx.x * 4 + w;
    float acc[NCLS];
    #pragma unroll
    for (int k = 0; k < NCLS; ++k) acc[k] = 0.0f;
    for (int k = lane; k < HID; k += 64) {
        float hv = __bfloat162float(h[b * HID + k]);
        #pragma unroll
        for (int cls = 0; cls < NCLS; ++cls) acc[cls] += hv * Wph[cls * HID + k];
    }
    #pragma unroll
    for (int cls = 0; cls < NCLS; ++cls) {
        float v = acc[cls];
        #pragma unroll
        for (int off = 32; off > 0; off >>= 1) v += __shfl_down(v, off);
        if (lane == 0) y[b * NCLS + cls] = v + bp[cls];
    }
}

extern "C" void kernel_launch(void* const* d_in, const int* in_sizes, int n_in,
                              void* d_out, int out_size, void* d_ws, size_t ws_size,
                              hipStream_t stream)
{
    const int*   x     = (const int*)d_in[0];
    const float* embed = (const float*)d_in[1];
    const float* Wgx   = (const float*)d_in[2];
    const float* Wix   = (const float*)d_in[3];
    const float* Wfx   = (const float*)d_in[4];
    const float* Wox   = (const float*)d_in[5];
    const float* Wgh   = (const float*)d_in[6];
    const float* Wih   = (const float*)d_in[7];
    const float* Wfh   = (const float*)d_in[8];
    const float* Woh   = (const float*)d_in[9];
    const float* Wph   = (const float*)d_in[10];
    const float* bg    = (const float*)d_in[11];
    const float* bi    = (const float*)d_in[12];
    const float* bf    = (const float*)d_in[13];
    const float* bo    = (const float*)d_in[14];
    const float* bp    = (const float*)d_in[15];
    float* out = (float*)d_out;

    char* ws = (char*)d_ws;
    __hip_bfloat16* whb  = (__hip_bfloat16*)(ws + OFF_WHB);
    float*          ptab = (float*)(ws + OFF_PTAB);
    __hip_bfloat16* h0   = (__hip_bfloat16*)(ws + OFF_H0);
    __hip_bfloat16* h1   = (__hip_bfloat16*)(ws + OFF_H1);
    unsigned*       bar  = (unsigned*)(ws + OFF_BAR);

    prep_kernel<<<16384, 256, 0, stream>>>(Wgh, Wih, Wfh, Woh, embed,
                                           Wgx, Wix, Wfx, Wox,
                                           bg, bi, bf, bo,
                                           whb, ptab, h0, h1, bar);

    lstm_persist<<<256, 256, 0, stream>>>(x, ptab, whb, h0, h1, bar);

    // T=256 even -> final h lives in h0.
    final_kernel<<<64, 256, 0, stream>>>(h0, Wph, bp, out);
}

// Round 12
// 1665.013 us; speedup vs baseline: 2.1984x; 1.2798x over previous
//
#include <hip/hip_runtime.h>
#include <hip/hip_bf16.h>

#define T_SEQ 256
#define BATCH 256
#define HID   1024
#define EMB   10
#define VOCABN 10
#define NCLS  10

typedef __attribute__((ext_vector_type(8))) short short8;
typedef __attribute__((ext_vector_type(4))) float floatx4;
typedef unsigned long long ull;

// ---- workspace layout (bytes) ----
#define OFF_WHB   0                                // 4096*1024 bf16 = 8 MB
#define OFF_PTAB  (8*1024*1024)                    // 10*4096 f32 = 160 KB
#define OFF_H0    (OFF_PTAB + 160*1024)            // 256*1024 bf16 = 512 KB
#define OFF_H1    (OFF_H0 + BATCH*HID*2)
#define OFF_BAR   (OFF_H1 + BATCH*HID*2)
// bar words: [0,1024) sig[bt][q][pwg][pw]; [1024,2048) mb[bt][q][cwg];
//            [2048,2304) XCD slot ctrs (1 per 32-word line)

// Spin bound: converts any broken-link hang into a diagnosable
// failed-verification run instead of a harness timeout (r3 lesson).
#define SPIN_BOUND (1u << 17)

// hwreg(HW_REG_XCC_ID=20, offset=0, width=32) -> 20 | (31<<11) = 63508
#define HWREG_XCC_ID_FULL 63508

__device__ __forceinline__ float fsig(float x) {
    return __builtin_amdgcn_rcpf(1.0f + __expf(-x));
}
__device__ __forceinline__ float ftanh(float x) {
    return 2.0f * fsig(2.0f * x) - 1.0f;
}

// TCC-executed atomic add returning old value. THE only always-fresh cross-CU
// read on gfx950 (r3..r11: plain/sc0 loads poll L1-stale; nt reads the stale
// memory-side copy; per-iteration buffer_inv poisons sibling waves' loads).
// Same-ADDRESS RMWs serialize at the TCC (~100cy) -> this design gives every
// RMW-hot word exactly 1-2 touchers.
__device__ __forceinline__ unsigned atomic_add_ret_l2(unsigned* p, unsigned v) {
    unsigned old;
    asm volatile("global_atomic_add %0, %1, %2, off sc0\n\ts_waitcnt vmcnt(0)"
                 : "=v"(old) : "v"(p), "v"(v) : "memory");
    return old;
}
__device__ __forceinline__ void atomic_add_l2(unsigned* p, unsigned v) {
    asm volatile("global_atomic_add %0, %1, off" :: "v"(p), "v"(v) : "memory");
}

// One-shot prep: cast Wh -> bf16 gate-major; build ptab; zero h0/h1 + sync words.
__global__ __launch_bounds__(256)
void prep_kernel(const float* __restrict__ Wgh, const float* __restrict__ Wih,
                 const float* __restrict__ Wfh, const float* __restrict__ Woh,
                 const float* __restrict__ embed,
                 const float* __restrict__ Wgx, const float* __restrict__ Wix,
                 const float* __restrict__ Wfx, const float* __restrict__ Wox,
                 const float* __restrict__ bg, const float* __restrict__ bi,
                 const float* __restrict__ bf, const float* __restrict__ bo,
                 __hip_bfloat16* __restrict__ whb, float* __restrict__ ptab,
                 __hip_bfloat16* __restrict__ h0, __hip_bfloat16* __restrict__ h1,
                 unsigned* __restrict__ bar)
{
    int idx = blockIdx.x * 256 + threadIdx.x;   // 0 .. 4194303
    {
        int gate = idx >> 20;
        int rem  = idx & 0xFFFFF;
        const float* W = (gate == 0) ? Wgh : (gate == 1) ? Wih : (gate == 2) ? Wfh : Woh;
        whb[idx] = __float2bfloat16(W[rem]);
    }
    if (idx < VOCABN * 4 * HID) {               // ptab[v*4096 + g]
        int v = idx >> 12;
        int g = idx & 4095;
        int gg = g >> 10;
        int j  = g & 1023;
        const float* Wx = (gg == 0) ? Wgx : (gg == 1) ? Wix : (gg == 2) ? Wfx : Wox;
        const float* bb = (gg == 0) ? bg  : (gg == 1) ? bi  : (gg == 2) ? bf  : bo;
        float s = bb[j];
        #pragma unroll
        for (int e = 0; e < EMB; ++e) s += embed[v * EMB + e] * Wx[j * EMB + e];
        ptab[idx] = s;
    }
    if (idx < BATCH * HID) {
        h0[idx] = __float2bfloat16(0.0f);
        h1[idx] = __float2bfloat16(0.0f);       // insurance: bounded values if raced
    }
    if (idx < 2304) bar[idx] = 0u;              // sig + mailboxes + slot ctrs
}

// Persistent LSTM, weights stationary in registers for all 256 timesteps.
// Grid 256 WGs x 256 thr; ~117KB LDS -> 1 WG/CU forced; 256 CUs -> pigeonhole
// gives exactly 32 WGs per XCD. Each WG reads its physical XCD (s_getreg
// XCC_ID) and claims (bt=xcd, ht=slot): producers/consumers of a batch group
// share one XCD; the h exchange lives in that XCD's L2.
//
// Sync (all-atomic, all distinct-address -> no TCC serialization):
//   - signal: producer wave (bt,ht,pw) drains its h stores (vmcnt 0) then
//     atomic-adds 1 to ITS OWN word sig[bt][ht>>3][ht&7][pw]. Early, per-wave
//     (r6 timing: post-barrier per-WG signals put barrier latency on the
//     chain, r9/r11 regressions).
//   - monitor: wave w of the WG with ht==w spins on its quarter's 32 sig
//     words (64-lane coalesced RMW, 2 lanes/word), then broadcasts +1 to the
//     32 mailboxes mb[bt][w][0..31] (32 parallel RMWs) and proceeds (its own
//     quarter is verified).
//   - consumers (all other waves): lane0 RMW-polls its PRIVATE mailbox
//     mb[bt][w][ht] (1 writer + 1 poller -> ~zero contention, always fresh).
//   r6 had 32 signalers + 32 pollers per quarter COUNTER, all serialized at
//   the TCC (~2-5k cy detect tail/step). Here every hot word has <=2 touchers.
//
//   - A-loads: ONE buffer_inv sc0 + s_waitcnt vmcnt(0) per wave per step,
//     then 16 plain dwordx4 in one L2 round trip (r6-proven fresh).
//   - x staged in LDS once (r9-proven): immune to the per-step L1 inv.
//
// WAR on the h ping-pong: h-stores of iter t happen after the red-barrier,
// i.e. after ALL 4 waves' spins(t) -> after all 32 WGs completed step t ->
// after their iter t-1 A-loads of the buffer being overwritten retired.
// Monitor hop preserves the implication (broadcast only after __all(sig>=t)).
__global__ __launch_bounds__(256, 1)
void lstm_persist(const int* __restrict__ x, const float* __restrict__ ptab,
                  const __hip_bfloat16* __restrict__ whb,
                  __hip_bfloat16* __restrict__ h0buf,
                  __hip_bfloat16* __restrict__ h1buf,
                  unsigned* __restrict__ bar)
{
    __shared__ float red[4 * 2 * 8 * 320];   // [wave][m][n][col*20+row] = 80 KB
    __shared__ float pt[VOCABN * 128];       // [v][g][jj2] = 5 KB
    __shared__ int   xs[32 * T_SEQ];         // [row][t] = 32 KB
    __shared__ int s_grp[2];

    const int tid  = threadIdx.x;
    const int w    = tid >> 6;
    const int lane = tid & 63;
    const int l16  = lane & 15;
    const int quad = lane >> 4;

    // ---- runtime XCD discovery + slot claim (correct under ANY dispatch map).
    if (tid == 0) {
        unsigned xcd = __builtin_amdgcn_s_getreg(HWREG_XCC_ID_FULL) & 7u;
        unsigned slot = atomic_add_ret_l2(bar + 2048 + xcd * 32, 1u);
        s_grp[0] = (int)xcd;
        s_grp[1] = (int)(slot & 31u);
    }
    __syncthreads();
    const int bt = s_grp[0];                  // batch group == physical XCD
    const int ht = s_grp[1];                  // 0..31 hidden tile (claim order)
    const int j0 = ht << 5;
    const int b0 = bt << 5;
    const int mw = w >> 1;                    // owned m-tile (post-reduction)
    const int jb = w & 1;                     // owned 16-col half of the 32-hid tile

    // Sync pointers.
    unsigned* sigbase = bar + (bt << 7);                         // sig[bt][..]
    unsigned* mbbase  = bar + 1024 + (bt << 7);                  // mb[bt][..]
    unsigned* sigmine = sigbase + ((ht >> 3) << 5) + ((ht & 7) << 2) + w;  // owned sig word
    unsigned* mbmine  = mbbase + (w << 5) + ht;                  // private mailbox
    const bool is_monitor = (ht == w);                           // wave w of WG ht==w

    // Stage ptab slice: pt[v*128 + g*32 + jj2]
    for (int i = tid; i < VOCABN * 128; i += 256) {
        int v = i >> 7, r = i & 127, g = r >> 5, jj2 = r & 31;
        pt[i] = ptab[v * 4096 + g * 1024 + j0 + jj2];
    }
    // Stage this group's x rows: xs[row*256 + t], coalesced.
    for (int i = tid; i < 32 * T_SEQ; i += 256) {
        int row = i >> 8, tt = i & 255;
        xs[i] = x[(b0 + row) * T_SEQ + tt];
    }

    // Stationary B fragments: n-frag n -> gate n>>1, col-half (n&1)*16.
    short8 Bf[8][8];
    #pragma unroll
    for (int n = 0; n < 8; ++n) {
        const short* p = (const short*)whb + (((size_t)(n >> 1)) << 20)
                       + (((size_t)(j0 + ((n & 1) << 4) + l16)) << 10)
                       + (w << 8) + (quad << 3);
        #pragma unroll
        for (int kc = 0; kc < 8; ++kc)
            Bf[n][kc] = *(const short8*)(p + kc * 32);
    }

    float cst[4] = {0.f, 0.f, 0.f, 0.f};
    __syncthreads();                          // pt + xs ready

    ull hinA  = (ull)h0buf;
    ull houtA = (ull)h1buf;
    const int brow = (mw << 4) + (quad << 2); // owned batch-row base (local)

    #pragma unroll 1
    for (int t = 0; t < T_SEQ; ++t) {
        // x fetch from LDS (independent of h readiness, inv-immune).
        int xv[4];
        #pragma unroll
        for (int r = 0; r < 4; ++r) xv[r] = xs[(brow + r) * T_SEQ + t];

        // ---- wait for quarter w of h_t.
        if (t) {
            unsigned tgt = (unsigned)t;
            if (is_monitor) {
                // 64-lane coalesced RMW over the 32 sig words (2 lanes/word).
                unsigned* sp = sigbase + (w << 5) + (lane & 31);
                for (unsigned it = 0; it < SPIN_BOUND; ++it) {
                    unsigned v = atomic_add_ret_l2(sp, 0u);
                    if (__all((int)(v >= tgt))) break;
                    __builtin_amdgcn_s_sleep(1);
                }
                // Broadcast to the 32 consumer-WG mailboxes of quarter w.
                if (lane < 32)
                    atomic_add_l2(mbbase + (w << 5) + lane, 1u);
            } else {
                // Private mailbox: 1 writer (monitor) + this single poller.
                if (lane == 0) {
                    for (unsigned it = 0; it < SPIN_BOUND; ++it) {
                        if (atomic_add_ret_l2(mbmine, 0u) >= tgt) break;
                        __builtin_amdgcn_s_sleep(1);
                    }
                }
            }
            // ONE L1-only invalidate per wave per step (completion waited) so
            // the plain A-loads below refill from the fresh local L2.
            asm volatile("buffer_inv sc0\n\ts_waitcnt vmcnt(0)" ::: "memory");
        }

        // ---- A-fragment loads: all 16 plain loads in flight, ONE L2 round trip.
        const ull* Au = (const ull*)hinA + (((size_t)(b0 + l16)) << 8) + (w << 6) + (quad << 1);
        short8 Af[2][8];
        #pragma unroll
        for (int kc = 0; kc < 8; ++kc)
            Af[0][kc] = *(const short8*)(Au + kc * 8);
        #pragma unroll
        for (int kc = 0; kc < 8; ++kc)
            Af[1][kc] = *(const short8*)(Au + 4096 + kc * 8);

        // ---- partial GEMM over this wave's K-slice: 2 m-tiles x 8 n-frags.
        floatx4 acc[2][8];
        #pragma unroll
        for (int m = 0; m < 2; ++m) {
            #pragma unroll
            for (int n = 0; n < 8; ++n) {
                floatx4 a = {0.f, 0.f, 0.f, 0.f};
                #pragma unroll
                for (int kc = 0; kc < 8; ++kc)
                    a = __builtin_amdgcn_mfma_f32_16x16x32_bf16(Af[m][kc], Bf[n][kc], a, 0, 0, 0);
                acc[m][n] = a;
            }
        }

        // ---- K-reduction through LDS; wave w owns (m=mw, col-half jb).
        #pragma unroll
        for (int m = 0; m < 2; ++m)
            #pragma unroll
            for (int n = 0; n < 8; ++n)
                *(floatx4*)&red[(((w * 2 + m) * 8 + n) * 320) + l16 * 20 + quad * 4] = acc[m][n];
        __syncthreads();

        floatx4 z[4];
        #pragma unroll
        for (int g = 0; g < 4; ++g) {
            int n = (g << 1) + jb;
            floatx4 s = *(floatx4*)&red[((mw * 8 + n) * 320) + l16 * 20 + quad * 4];
            #pragma unroll
            for (int wp = 1; wp < 4; ++wp)
                s += *(floatx4*)&red[(((wp * 2 + mw) * 8 + n) * 320) + l16 * 20 + quad * 4];
            z[g] = s;
        }

        // ---- gates + register-resident c + plain h store (write-through to local L2).
        __hip_bfloat16* ho = (__hip_bfloat16*)houtA;
        const int jcol = j0 + (jb << 4) + l16;
        #pragma unroll
        for (int r = 0; r < 4; ++r) {
            int pb = (xv[r] << 7) + (jb << 4) + l16;
            float zg = z[0][r] + pt[pb];
            float zi = z[1][r] + pt[pb + 32];
            float zf = z[2][r] + pt[pb + 64];
            float zo = z[3][r] + pt[pb + 96];
            float gv = ftanh(zg), iv = fsig(zi), fv = fsig(zf), ov = fsig(zo);
            float cn = gv * iv + cst[r] * fv;
            cst[r] = cn;
            ho[(((size_t)(b0 + brow + r)) << 10) + jcol] = __float2bfloat16(ftanh(cn) * ov);
        }

        // ---- per-wave early signal: drain THIS wave's h stores to the local
        // L2 (store-ack from TCC), then bump OWN sig word (distinct address).
        if (t != T_SEQ - 1) {
            asm volatile("s_waitcnt vmcnt(0)" ::: "memory");
            if (lane == 0)
                atomic_add_l2(sigmine, 1u);
        }

        // red-buffer WAR protection for the next step (off the signal path).
        __syncthreads();

        ull tmp = hinA; hinA = houtA; houtA = tmp;
    }
}

// y = h @ W_ph^T + b_p : one wave per batch row.
__global__ __launch_bounds__(256)
void final_kernel(const __hip_bfloat16* __restrict__ h, const float* __restrict__ Wph,
                  const float* __restrict__ bp, float* __restrict__ y)
{
    int w = threadIdx.x >> 6;
    int lane = threadIdx.x & 63;
    int b = blockIdx.x * 4 + w;
    float acc[NCLS];
    #pragma unroll
    for (int k = 0; k < NCLS; ++k) acc[k] = 0.0f;
    for (int k = lane; k < HID; k += 64) {
        float hv = __bfloat162float(h[b * HID + k]);
        #pragma unroll
        for (int cls = 0; cls < NCLS; ++cls) acc[cls] += hv * Wph[cls * HID + k];
    }
    #pragma unroll
    for (int cls = 0; cls < NCLS; ++cls) {
        float v = acc[cls];
        #pragma unroll
        for (int off = 32; off > 0; off >>= 1) v += __shfl_down(v, off);
        if (lane == 0) y[b * NCLS + cls] = v + bp[cls];
    }
}

extern "C" void kernel_launch(void* const* d_in, const int* in_sizes, int n_in,
                              void* d_out, int out_size, void* d_ws, size_t ws_size,
                              hipStream_t stream)
{
    const int*   x     = (const int*)d_in[0];
    const float* embed = (const float*)d_in[1];
    const float* Wgx   = (const float*)d_in[2];
    const float* Wix   = (const float*)d_in[3];
    const float* Wfx   = (const float*)d_in[4];
    const float* Wox   = (const float*)d_in[5];
    const float* Wgh   = (const float*)d_in[6];
    const float* Wih   = (const float*)d_in[7];
    const float* Wfh   = (const float*)d_in[8];
    const float* Woh   = (const float*)d_in[9];
    const float* Wph   = (const float*)d_in[10];
    const float* bg    = (const float*)d_in[11];
    const float* bi    = (const float*)d_in[12];
    const float* bf    = (const float*)d_in[13];
    const float* bo    = (const float*)d_in[14];
    const float* bp    = (const float*)d_in[15];
    float* out = (float*)d_out;

    char* ws = (char*)d_ws;
    __hip_bfloat16* whb  = (__hip_bfloat16*)(ws + OFF_WHB);
    float*          ptab = (float*)(ws + OFF_PTAB);
    __hip_bfloat16* h0   = (__hip_bfloat16*)(ws + OFF_H0);
    __hip_bfloat16* h1   = (__hip_bfloat16*)(ws + OFF_H1);
    unsigned*       bar  = (unsigned*)(ws + OFF_BAR);

    prep_kernel<<<16384, 256, 0, stream>>>(Wgh, Wih, Wfh, Woh, embed,
                                           Wgx, Wix, Wfx, Wox,
                                           bg, bi, bf, bo,
                                           whb, ptab, h0, h1, bar);

    lstm_persist<<<256, 256, 0, stream>>>(x, ptab, whb, h0, h1, bar);

    // T=256 even -> final h lives in h0.
    final_kernel<<<64, 256, 0, stream>>>(h0, Wph, bp, out);
}

// Round 13
// 1536.043 us; speedup vs baseline: 2.3829x; 1.0840x over previous
//
#include <hip/hip_runtime.h>
#include <hip/hip_bf16.h>

#define T_SEQ 256
#define BATCH 256
#define HID   1024
#define EMB   10
#define VOCABN 10
#define NCLS  10

typedef __attribute__((ext_vector_type(8))) short short8;
typedef __attribute__((ext_vector_type(4))) float floatx4;
typedef unsigned long long ull;

// ---- workspace layout (bytes) ----
#define OFF_WHB   0                                // 4096*1024 bf16 = 8 MB
#define OFF_PTAB  (8*1024*1024)                    // 10*4096 f32 = 160 KB
#define OFF_H0    (OFF_PTAB + 160*1024)            // 256*1024 bf16 = 512 KB
#define OFF_H1    (OFF_H0 + BATCH*HID*2)
#define OFF_BAR   (OFF_H1 + BATCH*HID*2)           // [0,1024) quarter ctrs (1/line); [1024,1280) XCD slot ctrs (1/line)

// Spin bound: converts any broken-link hang into a diagnosable
// failed-verification run instead of a harness timeout (r3 lesson).
#define SPIN_BOUND (1u << 17)

// hwreg(HW_REG_XCC_ID=20, offset=0, width=32) -> 20 | (31<<11) = 63508
#define HWREG_XCC_ID_FULL 63508

__device__ __forceinline__ float fsig(float x) {
    return __builtin_amdgcn_rcpf(1.0f + __expf(-x));
}
__device__ __forceinline__ float ftanh(float x) {
    return 2.0f * fsig(2.0f * x) - 1.0f;
}

// TCC-executed atomic add returning old value. The ONLY always-fresh cross-CU
// read on gfx950 (r3..r11: plain/sc0 loads poll L1-stale; nt reads the stale
// memory-side copy; per-iteration buffer_inv poisons sibling waves' loads).
// Each RMW = one fabric transaction; same-address RMWs serialize (~100cy).
// This round's design point: <=16 sig + ~8xiters poll RMWs per counter per
// step (r6 had ~130-160).
__device__ __forceinline__ unsigned atomic_add_ret_l2(unsigned* p, unsigned v) {
    unsigned old;
    asm volatile("global_atomic_add %0, %1, %2, off sc0\n\ts_waitcnt vmcnt(0)"
                 : "=v"(old) : "v"(p), "v"(v) : "memory");
    return old;
}
__device__ __forceinline__ void atomic_add_l2(unsigned* p, unsigned v) {
    asm volatile("global_atomic_add %0, %1, off" :: "v"(p), "v"(v) : "memory");
}

// One-shot prep: cast Wh -> bf16 gate-major; build ptab; zero h0/h1 + counters.
__global__ __launch_bounds__(256)
void prep_kernel(const float* __restrict__ Wgh, const float* __restrict__ Wih,
                 const float* __restrict__ Wfh, const float* __restrict__ Woh,
                 const float* __restrict__ embed,
                 const float* __restrict__ Wgx, const float* __restrict__ Wix,
                 const float* __restrict__ Wfx, const float* __restrict__ Wox,
                 const float* __restrict__ bg, const float* __restrict__ bi,
                 const float* __restrict__ bf, const float* __restrict__ bo,
                 __hip_bfloat16* __restrict__ whb, float* __restrict__ ptab,
                 __hip_bfloat16* __restrict__ h0, __hip_bfloat16* __restrict__ h1,
                 unsigned* __restrict__ bar)
{
    int idx = blockIdx.x * 256 + threadIdx.x;   // 0 .. 4194303
    {
        int gate = idx >> 20;
        int rem  = idx & 0xFFFFF;
        const float* W = (gate == 0) ? Wgh : (gate == 1) ? Wih : (gate == 2) ? Wfh : Woh;
        whb[idx] = __float2bfloat16(W[rem]);
    }
    if (idx < VOCABN * 4 * HID) {               // ptab[v*4096 + g]
        int v = idx >> 12;
        int g = idx & 4095;
        int gg = g >> 10;
        int j  = g & 1023;
        const float* Wx = (gg == 0) ? Wgx : (gg == 1) ? Wix : (gg == 2) ? Wfx : Wox;
        const float* bb = (gg == 0) ? bg  : (gg == 1) ? bi  : (gg == 2) ? bf  : bo;
        float s = bb[j];
        #pragma unroll
        for (int e = 0; e < EMB; ++e) s += embed[v * EMB + e] * Wx[j * EMB + e];
        ptab[idx] = s;
    }
    if (idx < BATCH * HID) {
        h0[idx] = __float2bfloat16(0.0f);
        h1[idx] = __float2bfloat16(0.0f);       // insurance: bounded values if raced
    }
    if (idx < 1280) bar[idx] = 0u;              // quarter ctrs + padded slot ctrs
}

// Persistent LSTM, weights stationary in registers for all 256 timesteps.
// Grid 256 WGs x 256 thr; ~117KB LDS -> 1 WG/CU forced; 256 CUs -> pigeonhole
// gives exactly 32 WGs per XCD. Each WG reads its physical XCD (s_getreg
// XCC_ID) and claims (bt=xcd, ht=slot): producers/consumers of a batch group
// share one XCD; the h exchange lives entirely in that XCD's L2.
//
// Sync v13 (targets r6's residual: same-address RMW queuing at the TCC):
//   - signal: per-WG EARLY last-arriver. Each wave drains its h-stores
//     (vmcnt 0) then lane0 ds_add_rtn's a monotone LDS counter; the wave that
//     sees old%4==3 is the WG's last -> it fires ONE global atomic to the
//     WG's produced-quarter counter. 8 signal RMWs/counter/step (r6: 32),
//     with r6's early timing (r9 showed post-barrier signaling costs ~1µs).
//   - poll: wave 0 only. Lanes 0-3 RMW-poll the group's 4 quarter counters
//     (one instruction/iter, 4 distinct-address transactions, parallel at
//     TCC; 8 pollers/counter instead of 32), break on __all(counters>=8t),
//     then release siblings via an LDS word. Sibling waves spin on LDS
//     (on-CU, free). Losing per-wave early start is free: the reduction
//     barrier releases at max(start)+compute either way.
//   - A-loads: ONE buffer_inv sc0 + s_waitcnt vmcnt(0) per wave per step,
//     then 16 plain dwordx4 in one L2 round trip (r6-proven fresh).
//   - x staged in LDS once (r9-proven): immune to the per-step L1 inv.
//   - All spins bounded (r3 lesson): a broken link fails verification
//     diagnosably instead of hanging.
//
// WAR on the h ping-pong is transitive: step-t+2 stores of buffer P happen
// after wave0 observed all 32 WGs' step-t+1 signals (all 4 quarters); each
// WG's t+1 signal postdates its 4 waves' h-drains, which postdate its
// reduction barrier at t+1, which postdates its step-t+1 A-loads (and its
// step-t A-loads of P) retiring.
__global__ __launch_bounds__(256, 1)
void lstm_persist(const int* __restrict__ x, const float* __restrict__ ptab,
                  const __hip_bfloat16* __restrict__ whb,
                  __hip_bfloat16* __restrict__ h0buf,
                  __hip_bfloat16* __restrict__ h1buf,
                  unsigned* __restrict__ bar)
{
    __shared__ float red[4 * 2 * 8 * 320];   // [wave][m][n][col*20+row] = 80 KB
    __shared__ float pt[VOCABN * 128];       // [v][g][jj2] = 5 KB
    __shared__ int   xs[32 * T_SEQ];         // [row][t] = 32 KB
    __shared__ int s_grp[2];
    __shared__ unsigned s_arrive;            // monotone: 4 adds per signaling step
    __shared__ unsigned s_ready;             // wave0 -> siblings release word

    const int tid  = threadIdx.x;
    const int w    = tid >> 6;
    const int lane = tid & 63;
    const int l16  = lane & 15;
    const int quad = lane >> 4;

    // ---- runtime XCD discovery + slot claim (correct under ANY dispatch map).
    if (tid == 0) {
        unsigned xcd = __builtin_amdgcn_s_getreg(HWREG_XCC_ID_FULL) & 7u;
        unsigned slot = atomic_add_ret_l2(bar + 1024 + xcd * 32, 1u);
        s_grp[0] = (int)xcd;
        s_grp[1] = (int)(slot & 31u);
        s_arrive = 0u;
        s_ready  = 0u;
    }
    __syncthreads();
    const int bt = s_grp[0];                  // batch group == physical XCD
    const int ht = s_grp[1];                  // 0..31 hidden tile (claim order)
    const int j0 = ht << 5;
    const int b0 = bt << 5;
    const int mw = w >> 1;                    // owned m-tile (post-reduction)
    const int jb = w & 1;                     // owned 16-col half of the 32-hid tile

    unsigned* qbase = bar + (bt << 7);                    // 4 quarter ctrs, 1/32-word line
    unsigned* sigq  = qbase + ((ht >> 3) << 5);           // quarter this WG produces

    // Stage ptab slice: pt[v*128 + g*32 + jj2]
    for (int i = tid; i < VOCABN * 128; i += 256) {
        int v = i >> 7, r = i & 127, g = r >> 5, jj2 = r & 31;
        pt[i] = ptab[v * 4096 + g * 1024 + j0 + jj2];
    }
    // Stage this group's x rows: xs[row*256 + t], coalesced.
    for (int i = tid; i < 32 * T_SEQ; i += 256) {
        int row = i >> 8, tt = i & 255;
        xs[i] = x[(b0 + row) * T_SEQ + tt];
    }

    // Stationary B fragments: n-frag n -> gate n>>1, col-half (n&1)*16.
    short8 Bf[8][8];
    #pragma unroll
    for (int n = 0; n < 8; ++n) {
        const short* p = (const short*)whb + (((size_t)(n >> 1)) << 20)
                       + (((size_t)(j0 + ((n & 1) << 4) + l16)) << 10)
                       + (w << 8) + (quad << 3);
        #pragma unroll
        for (int kc = 0; kc < 8; ++kc)
            Bf[n][kc] = *(const short8*)(p + kc * 32);
    }

    float cst[4] = {0.f, 0.f, 0.f, 0.f};
    __syncthreads();                          // pt + xs + sync words ready

    ull hinA  = (ull)h0buf;
    ull houtA = (ull)h1buf;
    const int brow = (mw << 4) + (quad << 2); // owned batch-row base (local)

    #pragma unroll 1
    for (int t = 0; t < T_SEQ; ++t) {
        // x fetch from LDS (independent of h readiness, inv-immune).
        int xv[4];
        #pragma unroll
        for (int r = 0; r < 4; ++r) xv[r] = xs[(brow + r) * T_SEQ + t];

        // ---- step gate: wave0 polls all 4 quarter counters (lanes 0-3,
        // distinct addresses -> parallel at the TCC); siblings spin on LDS.
        if (t) {
            unsigned tgt = (unsigned)(t << 3);          // 8 WG-signals per quarter
            if (w == 0) {
                unsigned* qp = qbase + ((lane & 3) << 5);
                for (unsigned it = 0; it < SPIN_BOUND; ++it) {
                    unsigned vv = 0xFFFFFFFFu;
                    if (lane < 4) vv = atomic_add_ret_l2(qp, 0u);
                    if (__all((int)(vv >= tgt))) break;
                    __builtin_amdgcn_s_sleep(1);
                }
                if (lane == 0)
                    *(volatile unsigned*)&s_ready = (unsigned)t;
            } else {
                for (unsigned it = 0; it < SPIN_BOUND; ++it) {
                    if (*(volatile unsigned*)&s_ready >= (unsigned)t) break;
                    __builtin_amdgcn_s_sleep(1);
                }
            }
            // ONE L1-only invalidate per wave per step (completion waited) so
            // the plain A-loads below refill from the fresh local L2
            // (r6-proven; r7's corruption = this waitcnt missing).
            asm volatile("buffer_inv sc0\n\ts_waitcnt vmcnt(0)" ::: "memory");
        }

        // ---- A-fragment loads: all 16 plain loads in flight, ONE L2 round trip.
        const ull* Au = (const ull*)hinA + (((size_t)(b0 + l16)) << 8) + (w << 6) + (quad << 1);
        short8 Af[2][8];
        #pragma unroll
        for (int kc = 0; kc < 8; ++kc)
            Af[0][kc] = *(const short8*)(Au + kc * 8);
        #pragma unroll
        for (int kc = 0; kc < 8; ++kc)
            Af[1][kc] = *(const short8*)(Au + 4096 + kc * 8);

        // ---- partial GEMM over this wave's K-slice: 2 m-tiles x 8 n-frags.
        floatx4 acc[2][8];
        #pragma unroll
        for (int m = 0; m < 2; ++m) {
            #pragma unroll
            for (int n = 0; n < 8; ++n) {
                floatx4 a = {0.f, 0.f, 0.f, 0.f};
                #pragma unroll
                for (int kc = 0; kc < 8; ++kc)
                    a = __builtin_amdgcn_mfma_f32_16x16x32_bf16(Af[m][kc], Bf[n][kc], a, 0, 0, 0);
                acc[m][n] = a;
            }
        }

        // ---- K-reduction through LDS; wave w owns (m=mw, col-half jb).
        #pragma unroll
        for (int m = 0; m < 2; ++m)
            #pragma unroll
            for (int n = 0; n < 8; ++n)
                *(floatx4*)&red[(((w * 2 + m) * 8 + n) * 320) + l16 * 20 + quad * 4] = acc[m][n];
        __syncthreads();

        floatx4 z[4];
        #pragma unroll
        for (int g = 0; g < 4; ++g) {
            int n = (g << 1) + jb;
            floatx4 s = *(floatx4*)&red[((mw * 8 + n) * 320) + l16 * 20 + quad * 4];
            #pragma unroll
            for (int wp = 1; wp < 4; ++wp)
                s += *(floatx4*)&red[(((wp * 2 + mw) * 8 + n) * 320) + l16 * 20 + quad * 4];
            z[g] = s;
        }

        // ---- gates + register-resident c + plain h store (write-through to local L2).
        __hip_bfloat16* ho = (__hip_bfloat16*)houtA;
        const int jcol = j0 + (jb << 4) + l16;
        #pragma unroll
        for (int r = 0; r < 4; ++r) {
            int pb = (xv[r] << 7) + (jb << 4) + l16;
            float zg = z[0][r] + pt[pb];
            float zi = z[1][r] + pt[pb + 32];
            float zf = z[2][r] + pt[pb + 64];
            float zo = z[3][r] + pt[pb + 96];
            float gv = ftanh(zg), iv = fsig(zi), fv = fsig(zf), ov = fsig(zo);
            float cn = gv * iv + cst[r] * fv;
            cst[r] = cn;
            ho[(((size_t)(b0 + brow + r)) << 10) + jcol] = __float2bfloat16(ftanh(cn) * ov);
        }

        // ---- per-WG early signal, last-arriver: this wave drains its own h
        // stores, bumps the LDS arrival counter; the 4th arriver fires the
        // single global signal (all 4 waves' stores then provably drained).
        if (t != T_SEQ - 1) {
            asm volatile("s_waitcnt vmcnt(0)" ::: "memory");
            if (lane == 0) {
                unsigned old = __hip_atomic_fetch_add(&s_arrive, 1u,
                                   __ATOMIC_RELAXED, __HIP_MEMORY_SCOPE_WORKGROUP);
                if ((old & 3u) == 3u)
                    atomic_add_l2(sigq, 1u);
            }
        }

        // red-buffer WAR protection for the next step (off the signal path).
        __syncthreads();

        ull tmp = hinA; hinA = houtA; houtA = tmp;
    }
}

// y = h @ W_ph^T + b_p : one wave per batch row.
__global__ __launch_bounds__(256)
void final_kernel(const __hip_bfloat16* __restrict__ h, const float* __restrict__ Wph,
                  const float* __restrict__ bp, float* __restrict__ y)
{
    int w = threadIdx.x >> 6;
    int lane = threadIdx.x & 63;
    int b = blockIdx.x * 4 + w;
    float acc[NCLS];
    #pragma unroll
    for (int k = 0; k < NCLS; ++k) acc[k] = 0.0f;
    for (int k = lane; k < HID; k += 64) {
        float hv = __bfloat162float(h[b * HID + k]);
        #pragma unroll
        for (int cls = 0; cls < NCLS; ++cls) acc[cls] += hv * Wph[cls * HID + k];
    }
    #pragma unroll
    for (int cls = 0; cls < NCLS; ++cls) {
        float v = acc[cls];
        #pragma unroll
        for (int off = 32; off > 0; off >>= 1) v += __shfl_down(v, off);
        if (lane == 0) y[b * NCLS + cls] = v + bp[cls];
    }
}

extern "C" void kernel_launch(void* const* d_in, const int* in_sizes, int n_in,
                              void* d_out, int out_size, void* d_ws, size_t ws_size,
                              hipStream_t stream)
{
    const int*   x     = (const int*)d_in[0];
    const float* embed = (const float*)d_in[1];
    const float* Wgx   = (const float*)d_in[2];
    const float* Wix   = (const float*)d_in[3];
    const float* Wfx   = (const float*)d_in[4];
    const float* Wox   = (const float*)d_in[5];
    const float* Wgh   = (const float*)d_in[6];
    const float* Wih   = (const float*)d_in[7];
    const float* Wfh   = (const float*)d_in[8];
    const float* Woh   = (const float*)d_in[9];
    const float* Wph   = (const float*)d_in[10];
    const float* bg    = (const float*)d_in[11];
    const float* bi    = (const float*)d_in[12];
    const float* bf    = (const float*)d_in[13];
    const float* bo    = (const float*)d_in[14];
    const float* bp    = (const float*)d_in[15];
    float* out = (float*)d_out;

    char* ws = (char*)d_ws;
    __hip_bfloat16* whb  = (__hip_bfloat16*)(ws + OFF_WHB);
    float*          ptab = (float*)(ws + OFF_PTAB);
    __hip_bfloat16* h0   = (__hip_bfloat16*)(ws + OFF_H0);
    __hip_bfloat16* h1   = (__hip_bfloat16*)(ws + OFF_H1);
    unsigned*       bar  = (unsigned*)(ws + OFF_BAR);

    prep_kernel<<<16384, 256, 0, stream>>>(Wgh, Wih, Wfh, Woh, embed,
                                           Wgx, Wix, Wfx, Wox,
                                           bg, bi, bf, bo,
                                           whb, ptab, h0, h1, bar);

    lstm_persist<<<256, 256, 0, stream>>>(x, ptab, whb, h0, h1, bar);

    // T=256 even -> final h lives in h0.
    final_kernel<<<64, 256, 0, stream>>>(h0, Wph, bp, out);
}